// Round 2
// 396.275 us; speedup vs baseline: 1.0451x; 1.0451x over previous
//
#include <hip/hip_runtime.h>
#include <hip/hip_bf16.h>
#include <cstdint>
#include <cstddef>

#define B_     2
#define E_     196608
#define XD_    128
#define NREC_  12288
#define EOUT_  128
#define LIN_   256
#define LOUT_  256
#define M_     (B_ * NREC_)   // 24576 FFN rows

typedef __attribute__((ext_vector_type(8))) short short8;
typedef __attribute__((ext_vector_type(4))) float f32x4;

__device__ __forceinline__ unsigned short f2bf(float f) {
    union { float f; unsigned u; } v; v.f = f;
    unsigned r = v.u + 0x7FFFu + ((v.u >> 16) & 1u);
    return (unsigned short)(r >> 16);
}

// ---- precompute combined FFN weights + edge-count histogram (fused) ----
// blocks 0..511: weight precompute
// blocks 512..703: count histogram, int4-vectorized (192 blocks * 1024 edges)
__global__ __launch_bounds__(256) void pre_count(
        const float* __restrict__ W2, const float* __restrict__ b2,
        const float* __restrict__ L1, const float* __restrict__ L2,
        unsigned short* __restrict__ L1T, unsigned short* __restrict__ L2T,
        float* __restrict__ v,
        const int* __restrict__ recv, int* __restrict__ cnt) {
    int bid = blockIdx.x;
    int n = threadIdx.x;    // 0..255
    if (bid < 128) {
        int j = bid;
        float a0 = 0.f, a1 = 0.f, a2 = 0.f, a3 = 0.f;
        for (int c = 0; c < 128; c += 4) {
            a0 = fmaf(W2[j * 128 + c + 0], L1[(c + 0) * 256 + n], a0);
            a1 = fmaf(W2[j * 128 + c + 1], L1[(c + 1) * 256 + n], a1);
            a2 = fmaf(W2[j * 128 + c + 2], L1[(c + 2) * 256 + n], a2);
            a3 = fmaf(W2[j * 128 + c + 3], L1[(c + 3) * 256 + n], a3);
        }
        L1T[n * 256 + j] = f2bf((a0 + a1) + (a2 + a3));
        if (j == 0) {
            float s0 = 0.f, s1 = 0.f;
            for (int c = 0; c < 128; c += 2) {
                s0 = fmaf(b2[c + 0], L1[(c + 0) * 256 + n], s0);
                s1 = fmaf(b2[c + 1], L1[(c + 1) * 256 + n], s1);
            }
            v[n] = s0 + s1;
        }
    } else if (bid < 256) {
        int k = bid;                          // 128..255
        L1T[n * 256 + k] = f2bf(L1[k * 256 + n]);
    } else if (bid < 512) {
        int k = bid - 256;                    // 0..255
        L2T[n * 256 + k] = f2bf(L2[k * 256 + n]);
    } else {
        int i = (bid - 512) * 1024 + n * 4;   // exactly covers E_
        int4 rv = *(const int4*)(recv + i);
        atomicAdd(&cnt[rv.x], 1);
        atomicAdd(&cnt[rv.y], 1);
        atomicAdd(&cnt[rv.z], 1);
        atomicAdd(&cnt[rv.w], 1);
    }
}

// ---- exclusive scan over 12288 counts: wave-shuffle scan, 2 barriers ----
__global__ __launch_bounds__(1024) void scan_kernel(const int* __restrict__ cnt,
                                                    int* __restrict__ rowStart,
                                                    int* __restrict__ cursor) {
    __shared__ int wsum[16];
    int tid  = threadIdx.x;
    int lane = tid & 63;
    int wave = tid >> 6;
    int base = tid * 12;
    int4 c0 = *(const int4*)(cnt + base);
    int4 c1 = *(const int4*)(cnt + base + 4);
    int4 c2 = *(const int4*)(cnt + base + 8);
    int arr[12] = {c0.x, c0.y, c0.z, c0.w, c1.x, c1.y, c1.z, c1.w,
                   c2.x, c2.y, c2.z, c2.w};
    int local[12];
    int s = 0;
    #pragma unroll
    for (int j = 0; j < 12; ++j) { local[j] = s; s += arr[j]; }
    // inclusive wave scan of per-thread sums
    int inc = s;
    #pragma unroll
    for (int off = 1; off < 64; off <<= 1) {
        int nb = __shfl_up(inc, off, 64);
        if (lane >= off) inc += nb;
    }
    if (lane == 63) wsum[wave] = inc;
    __syncthreads();
    if (tid < 64) {
        int wv = (tid < 16) ? wsum[tid] : 0;
        #pragma unroll
        for (int off = 1; off < 16; off <<= 1) {
            int nb = __shfl_up(wv, off, 64);
            if (lane >= off) wv += nb;
        }
        if (tid < 16) wsum[tid] = wv;   // inclusive wave prefix
    }
    __syncthreads();
    int wpre = (wave == 0) ? 0 : wsum[wave - 1];
    int excl = wpre + inc - s;
    #pragma unroll
    for (int j = 0; j < 12; ++j) local[j] += excl;
    *(int4*)(rowStart + base)     = make_int4(local[0], local[1], local[2], local[3]);
    *(int4*)(rowStart + base + 4) = make_int4(local[4], local[5], local[6], local[7]);
    *(int4*)(rowStart + base + 8) = make_int4(local[8], local[9], local[10], local[11]);
    *(int4*)(cursor + base)       = make_int4(local[0], local[1], local[2], local[3]);
    *(int4*)(cursor + base + 4)   = make_int4(local[4], local[5], local[6], local[7]);
    *(int4*)(cursor + base + 8)   = make_int4(local[8], local[9], local[10], local[11]);
    if (tid == 1023) rowStart[NREC_] = wpre + inc;   // == E_
}

// ---- fill CSR edge id lists (int4-vectorized) ----
__global__ __launch_bounds__(256) void fill_kernel(const int* __restrict__ recv,
                                                   int* __restrict__ cursor,
                                                   int* __restrict__ edge_ids) {
    int i = (blockIdx.x * 256 + threadIdx.x) * 4;     // 192 blocks cover E_
    int4 rv = *(const int4*)(recv + i);
    int p0 = atomicAdd(&cursor[rv.x], 1); edge_ids[p0] = i;
    int p1 = atomicAdd(&cursor[rv.y], 1); edge_ids[p1] = i + 1;
    int p2 = atomicAdd(&cursor[rv.z], 1); edge_ids[p2] = i + 2;
    int p3 = atomicAdd(&cursor[rv.w], 1); edge_ids[p3] = i + 3;
}

// ---- fused gather: float4 loads (16B/lane), 4 edge slots per block ----
// slot s = tid>>5 handles edges k0+s, k0+s+4, ...; lane covers 4 cols.
// Outputs: aggS[NREC][128] (batch-shared S), aggX[B][NREC][128].
__global__ __launch_bounds__(128) void gather_kernel(
        const float* __restrict__ x, const float* __restrict__ ea,
        const float* __restrict__ W1, const float* __restrict__ b1,
        const int* __restrict__ rowStart, const int* __restrict__ edge_ids,
        unsigned short* __restrict__ aggS, unsigned short* __restrict__ aggX) {
    __shared__ float red[2][3][128];
    int r    = blockIdx.x;
    int t    = threadIdx.x;          // 0..127
    int wave = t >> 6;
    int lane = t & 63;
    int slot = t >> 5;               // 0..3
    int q4   = (t & 31) * 4;         // column base
    int k0 = __builtin_amdgcn_readfirstlane(rowStart[r]);
    int k1 = __builtin_amdgcn_readfirstlane(rowStart[r + 1]);
    float4 w1r0 = *(const float4*)(W1 + q4);
    float4 w1r1 = *(const float4*)(W1 + 128 + q4);
    float4 w1r2 = *(const float4*)(W1 + 256 + q4);
    float4 w1r3 = *(const float4*)(W1 + 384 + q4);
    float4 bb   = *(const float4*)(b1 + q4);
    const float* xb = x + (size_t)E_ * 128;
    float4 aS = {0.f, 0.f, 0.f, 0.f};
    float4 a0 = {0.f, 0.f, 0.f, 0.f};
    float4 a1 = {0.f, 0.f, 0.f, 0.f};

    int k = k0 + slot;
    for (; k + 4 < k1; k += 8) {
        int eA = edge_ids[k];
        int eB = edge_ids[k + 4];
        float4 xaA = *(const float4*)(x  + (size_t)eA * 128 + q4);
        float4 xcA = *(const float4*)(xb + (size_t)eA * 128 + q4);
        float4 qA  = *(const float4*)(ea + (size_t)eA * 4);
        float4 xaB = *(const float4*)(x  + (size_t)eB * 128 + q4);
        float4 xcB = *(const float4*)(xb + (size_t)eB * 128 + q4);
        float4 qB  = *(const float4*)(ea + (size_t)eB * 4);
        float4 p;
        p.x = fmaf(qA.x, w1r0.x, fmaf(qA.y, w1r1.x, fmaf(qA.z, w1r2.x, fmaf(qA.w, w1r3.x, bb.x))));
        p.y = fmaf(qA.x, w1r0.y, fmaf(qA.y, w1r1.y, fmaf(qA.z, w1r2.y, fmaf(qA.w, w1r3.y, bb.y))));
        p.z = fmaf(qA.x, w1r0.z, fmaf(qA.y, w1r1.z, fmaf(qA.z, w1r2.z, fmaf(qA.w, w1r3.z, bb.z))));
        p.w = fmaf(qA.x, w1r0.w, fmaf(qA.y, w1r1.w, fmaf(qA.z, w1r2.w, fmaf(qA.w, w1r3.w, bb.w))));
        aS.x += p.x / (1.f + __expf(-p.x));
        aS.y += p.y / (1.f + __expf(-p.y));
        aS.z += p.z / (1.f + __expf(-p.z));
        aS.w += p.w / (1.f + __expf(-p.w));
        a0.x += xaA.x; a0.y += xaA.y; a0.z += xaA.z; a0.w += xaA.w;
        a1.x += xcA.x; a1.y += xcA.y; a1.z += xcA.z; a1.w += xcA.w;
        p.x = fmaf(qB.x, w1r0.x, fmaf(qB.y, w1r1.x, fmaf(qB.z, w1r2.x, fmaf(qB.w, w1r3.x, bb.x))));
        p.y = fmaf(qB.x, w1r0.y, fmaf(qB.y, w1r1.y, fmaf(qB.z, w1r2.y, fmaf(qB.w, w1r3.y, bb.y))));
        p.z = fmaf(qB.x, w1r0.z, fmaf(qB.y, w1r1.z, fmaf(qB.z, w1r2.z, fmaf(qB.w, w1r3.z, bb.z))));
        p.w = fmaf(qB.x, w1r0.w, fmaf(qB.y, w1r1.w, fmaf(qB.z, w1r2.w, fmaf(qB.w, w1r3.w, bb.w))));
        aS.x += p.x / (1.f + __expf(-p.x));
        aS.y += p.y / (1.f + __expf(-p.y));
        aS.z += p.z / (1.f + __expf(-p.z));
        aS.w += p.w / (1.f + __expf(-p.w));
        a0.x += xaB.x; a0.y += xaB.y; a0.z += xaB.z; a0.w += xaB.w;
        a1.x += xcB.x; a1.y += xcB.y; a1.z += xcB.z; a1.w += xcB.w;
    }
    if (k < k1) {
        int e0 = edge_ids[k];
        float4 xa = *(const float4*)(x  + (size_t)e0 * 128 + q4);
        float4 xc = *(const float4*)(xb + (size_t)e0 * 128 + q4);
        float4 qe = *(const float4*)(ea + (size_t)e0 * 4);
        float4 p;
        p.x = fmaf(qe.x, w1r0.x, fmaf(qe.y, w1r1.x, fmaf(qe.z, w1r2.x, fmaf(qe.w, w1r3.x, bb.x))));
        p.y = fmaf(qe.x, w1r0.y, fmaf(qe.y, w1r1.y, fmaf(qe.z, w1r2.y, fmaf(qe.w, w1r3.y, bb.y))));
        p.z = fmaf(qe.x, w1r0.z, fmaf(qe.y, w1r1.z, fmaf(qe.z, w1r2.z, fmaf(qe.w, w1r3.z, bb.z))));
        p.w = fmaf(qe.x, w1r0.w, fmaf(qe.y, w1r1.w, fmaf(qe.z, w1r2.w, fmaf(qe.w, w1r3.w, bb.w))));
        aS.x += p.x / (1.f + __expf(-p.x));
        aS.y += p.y / (1.f + __expf(-p.y));
        aS.z += p.z / (1.f + __expf(-p.z));
        aS.w += p.w / (1.f + __expf(-p.w));
        a0.x += xa.x; a0.y += xa.y; a0.z += xa.z; a0.w += xa.w;
        a1.x += xc.x; a1.y += xc.y; a1.z += xc.z; a1.w += xc.w;
    }
    // reduce slot pairs within each wave (lane ^ 32 swaps slots)
    aS.x += __shfl_xor(aS.x, 32, 64); aS.y += __shfl_xor(aS.y, 32, 64);
    aS.z += __shfl_xor(aS.z, 32, 64); aS.w += __shfl_xor(aS.w, 32, 64);
    a0.x += __shfl_xor(a0.x, 32, 64); a0.y += __shfl_xor(a0.y, 32, 64);
    a0.z += __shfl_xor(a0.z, 32, 64); a0.w += __shfl_xor(a0.w, 32, 64);
    a1.x += __shfl_xor(a1.x, 32, 64); a1.y += __shfl_xor(a1.y, 32, 64);
    a1.z += __shfl_xor(a1.z, 32, 64); a1.w += __shfl_xor(a1.w, 32, 64);
    if (lane < 32) {
        *(float4*)&red[wave][0][q4] = aS;
        *(float4*)&red[wave][1][q4] = a0;
        *(float4*)&red[wave][2][q4] = a1;
    }
    __syncthreads();
    float S  = red[0][0][t] + red[1][0][t];
    float X0 = red[0][1][t] + red[1][1][t];
    float X1 = red[0][2][t] + red[1][2][t];
    aggS[(size_t)r * 128 + t] = f2bf(S);
    aggX[(size_t)r * 128 + t] = f2bf(X0);
    aggX[(size_t)(NREC_ + r) * 128 + t] = f2bf(X1);
}

// ---- output FFN: out = silu(agg @ L1comb + c1 + cnt*v) @ L2 + c2 ----
// 32 rows per block (2 waves x 16 rows) -> 768 blocks (3/CU, balanced).
__global__ __launch_bounds__(128) void ffn_kernel(
        const unsigned short* __restrict__ aggS,
        const unsigned short* __restrict__ aggX,
        const unsigned short* __restrict__ L1T, const float* __restrict__ c1,
        const unsigned short* __restrict__ L2T, const float* __restrict__ c2,
        const float* __restrict__ v, const int* __restrict__ cnt,
        float* __restrict__ out) {
    __shared__ unsigned short T[32][264];
    int tid  = threadIdx.x;
    int wave = tid >> 6;        // 0..1
    int lane = tid & 63;
    int quad = lane >> 4;
    int l16  = lane & 15;
    int m0 = blockIdx.x * 32 + wave * 16;
    int b  = (blockIdx.x * 32) / NREC_;       // uniform per block (NREC_%32==0)
    int r0 = m0 - b * NREC_;

    float cntv[4];
    #pragma unroll
    for (int rr = 0; rr < 4; ++rr)
        cntv[rr] = (float)cnt[r0 + quad * 4 + rr];

    // A fragments: cols 0..127 from shared S, cols 128..255 from per-batch X
    short8 afrag[8];
    const unsigned short* aS = aggS + (size_t)(r0 + l16) * 128 + quad * 8;
    const unsigned short* aX = aggX + ((size_t)b * NREC_ + r0 + l16) * 128 + quad * 8;
    #pragma unroll
    for (int ks = 0; ks < 4; ++ks) {
        afrag[ks]     = *(const short8*)(aS + ks * 32);
        afrag[ks + 4] = *(const short8*)(aX + ks * 32);
    }

    #pragma unroll 2
    for (int nt = 0; nt < 16; ++nt) {
        f32x4 acc = {0.f, 0.f, 0.f, 0.f};
        const unsigned short* bptr = L1T + (size_t)(nt * 16 + l16) * 256 + quad * 8;
        #pragma unroll
        for (int ks = 0; ks < 8; ++ks) {
            short8 bfrag = *(const short8*)(bptr + ks * 32);
            acc = __builtin_amdgcn_mfma_f32_16x16x32_bf16(afrag[ks], bfrag, acc, 0, 0, 0);
        }
        #pragma unroll
        for (int rr = 0; rr < 4; ++rr) {
            int row = quad * 4 + rr;
            int col = nt * 16 + l16;
            float pv = acc[rr] + c1[col] + cntv[rr] * v[col];
            pv = pv / (1.f + __expf(-pv));
            T[wave * 16 + row][col] = f2bf(pv);
        }
    }
    __syncthreads();

    short8 afrag2[8];
    #pragma unroll
    for (int ks = 0; ks < 8; ++ks)
        afrag2[ks] = *(const short8*)&T[wave * 16 + l16][ks * 32 + quad * 8];

    #pragma unroll 2
    for (int nt = 0; nt < 16; ++nt) {
        f32x4 acc = {0.f, 0.f, 0.f, 0.f};
        const unsigned short* bptr = L2T + (size_t)(nt * 16 + l16) * 256 + quad * 8;
        #pragma unroll
        for (int ks = 0; ks < 8; ++ks) {
            short8 bfrag = *(const short8*)(bptr + ks * 32);
            acc = __builtin_amdgcn_mfma_f32_16x16x32_bf16(afrag2[ks], bfrag, acc, 0, 0, 0);
        }
        #pragma unroll
        for (int rr = 0; rr < 4; ++rr) {
            int row = m0 + quad * 4 + rr;
            int col = nt * 16 + l16;
            out[(size_t)row * 256 + col] = acc[rr] + c2[col];
        }
    }
}

extern "C" void kernel_launch(void* const* d_in, const int* in_sizes, int n_in,
                              void* d_out, int out_size, void* d_ws, size_t ws_size,
                              hipStream_t stream) {
    const float* x          = (const float*)d_in[0];
    const float* edge_attr  = (const float*)d_in[1];
    const int*   edge_index = (const int*)d_in[2];
    const float* W1 = (const float*)d_in[3];
    const float* b1 = (const float*)d_in[4];
    const float* W2 = (const float*)d_in[5];
    const float* b2 = (const float*)d_in[6];
    const float* L1 = (const float*)d_in[7];
    const float* c1 = (const float*)d_in[8];
    const float* L2 = (const float*)d_in[9];
    const float* c2 = (const float*)d_in[10];
    float* out = (float*)d_out;

    // workspace layout (16B aligned)
    int* cnt      = (int*)d_ws;                 // 12288
    int* rowStart = cnt + NREC_;                // 12289 (pad to 12292)
    int* cursor   = rowStart + NREC_ + 4;       // 12288
    int* edge_ids = cursor + NREC_;             // 196608
    unsigned short* aggS = (unsigned short*)(edge_ids + E_);   // NREC_*128
    unsigned short* aggX = aggS + (size_t)NREC_ * 128;         // B_*NREC_*128
    unsigned short* L1T = aggX + (size_t)B_ * NREC_ * 128;     // 65536
    unsigned short* L2T = L1T + 256 * 256;                     // 65536
    float* v = (float*)(L2T + 256 * 256);                      // 256

    const int* recv = edge_index + E_;   // edge_index[1]

    hipMemsetAsync(cnt, 0, NREC_ * sizeof(int), stream);
    pre_count<<<704, 256, 0, stream>>>(W2, b2, L1, L2, L1T, L2T, v, recv, cnt);
    scan_kernel<<<1, 1024, 0, stream>>>(cnt, rowStart, cursor);
    fill_kernel<<<192, 256, 0, stream>>>(recv, cursor, edge_ids);
    gather_kernel<<<NREC_, 128, 0, stream>>>(x, edge_attr, W1, b1,
                                             rowStart, edge_ids, aggS, aggX);
    ffn_kernel<<<M_ / 32, 128, 0, stream>>>(aggS, aggX, L1T, c1, L2T, c2, v, cnt, out);
}

// Round 3
// 379.798 us; speedup vs baseline: 1.0905x; 1.0434x over previous
//
#include <hip/hip_runtime.h>
#include <hip/hip_bf16.h>
#include <cstdint>
#include <cstddef>

#define B_     2
#define E_     196608
#define XD_    128
#define NREC_  12288
#define CAP_   96                 // bucket capacity per receiver (mean=16, P(>96)~1e-40)
#define M_     (B_ * NREC_)

typedef __attribute__((ext_vector_type(8))) short short8;
typedef __attribute__((ext_vector_type(4))) float f32x4;
typedef __attribute__((ext_vector_type(4))) unsigned short ushort4v;

__device__ __forceinline__ unsigned short f2bf(float f) {
    union { float f; unsigned u; } v; v.f = f;
    unsigned r = v.u + 0x7FFFu + ((v.u >> 16) & 1u);
    return (unsigned short)(r >> 16);
}

// ---- fused: FFN weight precompute (blocks 0..511) + bucket count/fill (512..703) ----
// L1T[n][k]: k<128 : (W2@L1_top)[k][n]; k>=128 : L1[k][n].  L2T[n][k] = L2[k][n].
// v[n] = sum_c b2[c]*L1[c][n]  (scaled by cnt in mega).
__global__ __launch_bounds__(256) void pre_fill(
        const float* __restrict__ W2, const float* __restrict__ b2,
        const float* __restrict__ L1, const float* __restrict__ L2,
        unsigned short* __restrict__ L1T, unsigned short* __restrict__ L2T,
        float* __restrict__ v,
        const int* __restrict__ recv, int* __restrict__ cnt,
        int* __restrict__ bucket) {
    int bid = blockIdx.x;
    int n = threadIdx.x;    // 0..255
    if (bid < 128) {
        int j = bid;
        float a0 = 0.f, a1 = 0.f, a2 = 0.f, a3 = 0.f;
        for (int c = 0; c < 128; c += 4) {
            a0 = fmaf(W2[j * 128 + c + 0], L1[(c + 0) * 256 + n], a0);
            a1 = fmaf(W2[j * 128 + c + 1], L1[(c + 1) * 256 + n], a1);
            a2 = fmaf(W2[j * 128 + c + 2], L1[(c + 2) * 256 + n], a2);
            a3 = fmaf(W2[j * 128 + c + 3], L1[(c + 3) * 256 + n], a3);
        }
        L1T[n * 256 + j] = f2bf((a0 + a1) + (a2 + a3));
        if (j == 0) {
            float s0 = 0.f, s1 = 0.f;
            for (int c = 0; c < 128; c += 2) {
                s0 = fmaf(b2[c + 0], L1[(c + 0) * 256 + n], s0);
                s1 = fmaf(b2[c + 1], L1[(c + 1) * 256 + n], s1);
            }
            v[n] = s0 + s1;
        }
    } else if (bid < 256) {
        int k = bid;                          // 128..255
        L1T[n * 256 + k] = f2bf(L1[k * 256 + n]);
    } else if (bid < 512) {
        int k = bid - 256;                    // 0..255
        L2T[n * 256 + k] = f2bf(L2[k * 256 + n]);
    } else {
        int i = (bid - 512) * 1024 + n * 4;   // 192 blocks * 1024 edges == E_
        int4 rv = *(const int4*)(recv + i);
        int p0 = atomicAdd(&cnt[rv.x], 1);
        if (p0 < CAP_) bucket[(size_t)rv.x * CAP_ + p0] = i;
        int p1 = atomicAdd(&cnt[rv.y], 1);
        if (p1 < CAP_) bucket[(size_t)rv.y * CAP_ + p1] = i + 1;
        int p2 = atomicAdd(&cnt[rv.z], 1);
        if (p2 < CAP_) bucket[(size_t)rv.z * CAP_ + p2] = i + 2;
        int p3 = atomicAdd(&cnt[rv.w], 1);
        if (p3 < CAP_) bucket[(size_t)rv.w * CAP_ + p3] = i + 3;
    }
}

// ---- mega: fused gather (edges -> S,X0,X1 in LDS) + 2-layer MFMA FFN ----
// Block owns 16 receiver rows. Gather: 4 slots of 32 lanes, each slot owns one
// row at a time (4 rounds); lane covers 4 cols via float4 (16B/lane loads).
// FFN: wave0 = batch0 [S|X0], wave1 = batch1 [S|X1]; 16x16x32 bf16 MFMA.
__global__ __launch_bounds__(128) void mega_kernel(
        const float* __restrict__ x, const float* __restrict__ ea,
        const float* __restrict__ W1, const float* __restrict__ b1,
        const int* __restrict__ cnt, const int* __restrict__ bucket,
        const unsigned short* __restrict__ L1T, const float* __restrict__ c1,
        const unsigned short* __restrict__ L2T, const float* __restrict__ c2,
        const float* __restrict__ v, float* __restrict__ out) {
    __shared__ unsigned short Sb[16][136];
    __shared__ unsigned short X0b[16][136];
    __shared__ unsigned short X1b[16][136];
    __shared__ unsigned short T[32][264];
    int tid  = threadIdx.x;          // 0..127
    int r0   = blockIdx.x * 16;
    int slot = tid >> 5;             // 0..3
    int l32  = tid & 31;
    int q4   = l32 * 4;

    float4 w1r0 = *(const float4*)(W1 + q4);
    float4 w1r1 = *(const float4*)(W1 + 128 + q4);
    float4 w1r2 = *(const float4*)(W1 + 256 + q4);
    float4 w1r3 = *(const float4*)(W1 + 384 + q4);
    float4 bb   = *(const float4*)(b1 + q4);
    const float* xb = x + (size_t)E_ * 128;

    #pragma unroll
    for (int rr8 = 0; rr8 < 4; ++rr8) {
        int row = rr8 * 4 + slot;            // 0..15
        int r = r0 + row;
        int cr = cnt[r];
        cr = (cr > CAP_) ? CAP_ : cr;        // impossible-overflow guard
        const int* bk = bucket + (size_t)r * CAP_;
        float4 aS = {0.f, 0.f, 0.f, 0.f};
        float4 a0 = {0.f, 0.f, 0.f, 0.f};
        float4 a1 = {0.f, 0.f, 0.f, 0.f};
        int k = 0;
        for (; k + 2 <= cr; k += 2) {
            int e0 = bk[k];
            int e1 = bk[k + 1];
            float4 xa0 = *(const float4*)(x  + (size_t)e0 * 128 + q4);
            float4 xc0 = *(const float4*)(xb + (size_t)e0 * 128 + q4);
            float4 q0  = *(const float4*)(ea + (size_t)e0 * 4);
            float4 xa1 = *(const float4*)(x  + (size_t)e1 * 128 + q4);
            float4 xc1 = *(const float4*)(xb + (size_t)e1 * 128 + q4);
            float4 q1  = *(const float4*)(ea + (size_t)e1 * 4);
            float4 p;
            p.x = fmaf(q0.x, w1r0.x, fmaf(q0.y, w1r1.x, fmaf(q0.z, w1r2.x, fmaf(q0.w, w1r3.x, bb.x))));
            p.y = fmaf(q0.x, w1r0.y, fmaf(q0.y, w1r1.y, fmaf(q0.z, w1r2.y, fmaf(q0.w, w1r3.y, bb.y))));
            p.z = fmaf(q0.x, w1r0.z, fmaf(q0.y, w1r1.z, fmaf(q0.z, w1r2.z, fmaf(q0.w, w1r3.z, bb.z))));
            p.w = fmaf(q0.x, w1r0.w, fmaf(q0.y, w1r1.w, fmaf(q0.z, w1r2.w, fmaf(q0.w, w1r3.w, bb.w))));
            aS.x += p.x / (1.f + __expf(-p.x));
            aS.y += p.y / (1.f + __expf(-p.y));
            aS.z += p.z / (1.f + __expf(-p.z));
            aS.w += p.w / (1.f + __expf(-p.w));
            a0.x += xa0.x; a0.y += xa0.y; a0.z += xa0.z; a0.w += xa0.w;
            a1.x += xc0.x; a1.y += xc0.y; a1.z += xc0.z; a1.w += xc0.w;
            p.x = fmaf(q1.x, w1r0.x, fmaf(q1.y, w1r1.x, fmaf(q1.z, w1r2.x, fmaf(q1.w, w1r3.x, bb.x))));
            p.y = fmaf(q1.x, w1r0.y, fmaf(q1.y, w1r1.y, fmaf(q1.z, w1r2.y, fmaf(q1.w, w1r3.y, bb.y))));
            p.z = fmaf(q1.x, w1r0.z, fmaf(q1.y, w1r1.z, fmaf(q1.z, w1r2.z, fmaf(q1.w, w1r3.z, bb.z))));
            p.w = fmaf(q1.x, w1r0.w, fmaf(q1.y, w1r1.w, fmaf(q1.z, w1r2.w, fmaf(q1.w, w1r3.w, bb.w))));
            aS.x += p.x / (1.f + __expf(-p.x));
            aS.y += p.y / (1.f + __expf(-p.y));
            aS.z += p.z / (1.f + __expf(-p.z));
            aS.w += p.w / (1.f + __expf(-p.w));
            a0.x += xa1.x; a0.y += xa1.y; a0.z += xa1.z; a0.w += xa1.w;
            a1.x += xc1.x; a1.y += xc1.y; a1.z += xc1.z; a1.w += xc1.w;
        }
        if (k < cr) {
            int e0 = bk[k];
            float4 xa0 = *(const float4*)(x  + (size_t)e0 * 128 + q4);
            float4 xc0 = *(const float4*)(xb + (size_t)e0 * 128 + q4);
            float4 q0  = *(const float4*)(ea + (size_t)e0 * 4);
            float4 p;
            p.x = fmaf(q0.x, w1r0.x, fmaf(q0.y, w1r1.x, fmaf(q0.z, w1r2.x, fmaf(q0.w, w1r3.x, bb.x))));
            p.y = fmaf(q0.x, w1r0.y, fmaf(q0.y, w1r1.y, fmaf(q0.z, w1r2.y, fmaf(q0.w, w1r3.y, bb.y))));
            p.z = fmaf(q0.x, w1r0.z, fmaf(q0.y, w1r1.z, fmaf(q0.z, w1r2.z, fmaf(q0.w, w1r3.z, bb.z))));
            p.w = fmaf(q0.x, w1r0.w, fmaf(q0.y, w1r1.w, fmaf(q0.z, w1r2.w, fmaf(q0.w, w1r3.w, bb.w))));
            aS.x += p.x / (1.f + __expf(-p.x));
            aS.y += p.y / (1.f + __expf(-p.y));
            aS.z += p.z / (1.f + __expf(-p.z));
            aS.w += p.w / (1.f + __expf(-p.w));
            a0.x += xa0.x; a0.y += xa0.y; a0.z += xa0.z; a0.w += xa0.w;
            a1.x += xc0.x; a1.y += xc0.y; a1.z += xc0.z; a1.w += xc0.w;
        }
        ushort4v sS = {f2bf(aS.x), f2bf(aS.y), f2bf(aS.z), f2bf(aS.w)};
        ushort4v s0 = {f2bf(a0.x), f2bf(a0.y), f2bf(a0.z), f2bf(a0.w)};
        ushort4v s1 = {f2bf(a1.x), f2bf(a1.y), f2bf(a1.z), f2bf(a1.w)};
        *(ushort4v*)&Sb[row][q4]  = sS;
        *(ushort4v*)&X0b[row][q4] = s0;
        *(ushort4v*)&X1b[row][q4] = s1;
    }
    __syncthreads();

    // ---- FFN phase ----
    int wave = tid >> 6;        // batch index (0..1)
    int lane = tid & 63;
    int quad = lane >> 4;
    int l16  = lane & 15;

    float cntv[4];
    #pragma unroll
    for (int rr = 0; rr < 4; ++rr)
        cntv[rr] = (float)cnt[r0 + quad * 4 + rr];

    short8 afrag[8];
    #pragma unroll
    for (int ks = 0; ks < 4; ++ks) {
        afrag[ks] = *(const short8*)&Sb[l16][quad * 8 + ks * 32];
        afrag[ks + 4] = wave ? *(const short8*)&X1b[l16][quad * 8 + ks * 32]
                             : *(const short8*)&X0b[l16][quad * 8 + ks * 32];
    }

    #pragma unroll 2
    for (int nt = 0; nt < 16; ++nt) {
        f32x4 acc = {0.f, 0.f, 0.f, 0.f};
        const unsigned short* bptr = L1T + (size_t)(nt * 16 + l16) * 256 + quad * 8;
        #pragma unroll
        for (int ks = 0; ks < 8; ++ks) {
            short8 bfrag = *(const short8*)(bptr + ks * 32);
            acc = __builtin_amdgcn_mfma_f32_16x16x32_bf16(afrag[ks], bfrag, acc, 0, 0, 0);
        }
        #pragma unroll
        for (int rr = 0; rr < 4; ++rr) {
            int col = nt * 16 + l16;
            float pv = acc[rr] + c1[col] + cntv[rr] * v[col];
            pv = pv / (1.f + __expf(-pv));
            T[wave * 16 + quad * 4 + rr][col] = f2bf(pv);
        }
    }
    __syncthreads();

    short8 afrag2[8];
    #pragma unroll
    for (int ks = 0; ks < 8; ++ks)
        afrag2[ks] = *(const short8*)&T[wave * 16 + l16][ks * 32 + quad * 8];

    #pragma unroll 2
    for (int nt = 0; nt < 16; ++nt) {
        f32x4 acc = {0.f, 0.f, 0.f, 0.f};
        const unsigned short* bptr = L2T + (size_t)(nt * 16 + l16) * 256 + quad * 8;
        #pragma unroll
        for (int ks = 0; ks < 8; ++ks) {
            short8 bfrag = *(const short8*)(bptr + ks * 32);
            acc = __builtin_amdgcn_mfma_f32_16x16x32_bf16(afrag2[ks], bfrag, acc, 0, 0, 0);
        }
        #pragma unroll
        for (int rr = 0; rr < 4; ++rr) {
            size_t row = (size_t)wave * NREC_ + r0 + quad * 4 + rr;
            int col = nt * 16 + l16;
            out[row * 256 + col] = acc[rr] + c2[col];
        }
    }
}

extern "C" void kernel_launch(void* const* d_in, const int* in_sizes, int n_in,
                              void* d_out, int out_size, void* d_ws, size_t ws_size,
                              hipStream_t stream) {
    const float* x          = (const float*)d_in[0];
    const float* edge_attr  = (const float*)d_in[1];
    const int*   edge_index = (const int*)d_in[2];
    const float* W1 = (const float*)d_in[3];
    const float* b1 = (const float*)d_in[4];
    const float* W2 = (const float*)d_in[5];
    const float* b2 = (const float*)d_in[6];
    const float* L1 = (const float*)d_in[7];
    const float* c1 = (const float*)d_in[8];
    const float* L2 = (const float*)d_in[9];
    const float* c2 = (const float*)d_in[10];
    float* out = (float*)d_out;

    // workspace layout (16B aligned)
    int* cnt    = (int*)d_ws;                          // 12288 ints
    int* bucket = cnt + NREC_;                         // 12288*96 ints
    unsigned short* L1T = (unsigned short*)(bucket + (size_t)NREC_ * CAP_);  // 65536
    unsigned short* L2T = L1T + 256 * 256;             // 65536
    float* v = (float*)(L2T + 256 * 256);              // 256

    const int* recv = edge_index + E_;   // edge_index[1]

    hipMemsetAsync(cnt, 0, NREC_ * sizeof(int), stream);
    pre_fill<<<704, 256, 0, stream>>>(W2, b2, L1, L2, L1T, L2T, v, recv, cnt, bucket);
    mega_kernel<<<NREC_ / 16, 128, 0, stream>>>(x, edge_attr, W1, b1, cnt, bucket,
                                                L1T, c1, L2T, c2, v, out);
}

// Round 4
// 368.467 us; speedup vs baseline: 1.1240x; 1.0308x over previous
//
#include <hip/hip_runtime.h>
#include <hip/hip_bf16.h>
#include <cstdint>
#include <cstddef>

#define B_     2
#define E_     196608
#define XD_    128
#define NREC_  12288
#define CAP_   96                 // bucket capacity per receiver (mean=16, P(>96)~1e-40)
#define M_     (B_ * NREC_)

typedef __attribute__((ext_vector_type(8))) short short8;
typedef __attribute__((ext_vector_type(4))) float f32x4;
typedef __attribute__((ext_vector_type(4))) unsigned short ushort4v;

__device__ __forceinline__ unsigned short f2bf(float f) {
    union { float f; unsigned u; } v; v.f = f;
    unsigned r = v.u + 0x7FFFu + ((v.u >> 16) & 1u);
    return (unsigned short)(r >> 16);
}

// ---- fused: FFN weight precompute (blocks 0..511) + bucket count/fill (512..703) ----
__global__ __launch_bounds__(256) void pre_fill(
        const float* __restrict__ W2, const float* __restrict__ b2,
        const float* __restrict__ L1, const float* __restrict__ L2,
        unsigned short* __restrict__ L1T, unsigned short* __restrict__ L2T,
        float* __restrict__ v,
        const int* __restrict__ recv, int* __restrict__ cnt,
        int* __restrict__ bucket) {
    int bid = blockIdx.x;
    int n = threadIdx.x;    // 0..255
    if (bid < 128) {
        int j = bid;
        float a0 = 0.f, a1 = 0.f, a2 = 0.f, a3 = 0.f;
        for (int c = 0; c < 128; c += 4) {
            a0 = fmaf(W2[j * 128 + c + 0], L1[(c + 0) * 256 + n], a0);
            a1 = fmaf(W2[j * 128 + c + 1], L1[(c + 1) * 256 + n], a1);
            a2 = fmaf(W2[j * 128 + c + 2], L1[(c + 2) * 256 + n], a2);
            a3 = fmaf(W2[j * 128 + c + 3], L1[(c + 3) * 256 + n], a3);
        }
        L1T[n * 256 + j] = f2bf((a0 + a1) + (a2 + a3));
        if (j == 0) {
            float s0 = 0.f, s1 = 0.f;
            for (int c = 0; c < 128; c += 2) {
                s0 = fmaf(b2[c + 0], L1[(c + 0) * 256 + n], s0);
                s1 = fmaf(b2[c + 1], L1[(c + 1) * 256 + n], s1);
            }
            v[n] = s0 + s1;
        }
    } else if (bid < 256) {
        int k = bid;                          // 128..255
        L1T[n * 256 + k] = f2bf(L1[k * 256 + n]);
    } else if (bid < 512) {
        int k = bid - 256;                    // 0..255
        L2T[n * 256 + k] = f2bf(L2[k * 256 + n]);
    } else {
        int i = (bid - 512) * 1024 + n * 4;   // 192 blocks * 1024 edges == E_
        int4 rv = *(const int4*)(recv + i);
        int p0 = atomicAdd(&cnt[rv.x], 1);
        if (p0 < CAP_) bucket[(size_t)rv.x * CAP_ + p0] = i;
        int p1 = atomicAdd(&cnt[rv.y], 1);
        if (p1 < CAP_) bucket[(size_t)rv.y * CAP_ + p1] = i + 1;
        int p2 = atomicAdd(&cnt[rv.z], 1);
        if (p2 < CAP_) bucket[(size_t)rv.z * CAP_ + p2] = i + 2;
        int p3 = atomicAdd(&cnt[rv.w], 1);
        if (p3 < CAP_) bucket[(size_t)rv.w * CAP_ + p3] = i + 3;
    }
}

// MLP + accumulate for one edge (SiLU of 4->128 embed, plus x sums)
#define EDGE_ACC(qv, xav, xcv)                                                        \
    {                                                                                 \
        float4 p;                                                                     \
        p.x = fmaf(qv.x, w1r0.x, fmaf(qv.y, w1r1.x, fmaf(qv.z, w1r2.x, fmaf(qv.w, w1r3.x, bb.x)))); \
        p.y = fmaf(qv.x, w1r0.y, fmaf(qv.y, w1r1.y, fmaf(qv.z, w1r2.y, fmaf(qv.w, w1r3.y, bb.y)))); \
        p.z = fmaf(qv.x, w1r0.z, fmaf(qv.y, w1r1.z, fmaf(qv.z, w1r2.z, fmaf(qv.w, w1r3.z, bb.z)))); \
        p.w = fmaf(qv.x, w1r0.w, fmaf(qv.y, w1r1.w, fmaf(qv.z, w1r2.w, fmaf(qv.w, w1r3.w, bb.w)))); \
        aS.x += p.x / (1.f + __expf(-p.x));                                           \
        aS.y += p.y / (1.f + __expf(-p.y));                                           \
        aS.z += p.z / (1.f + __expf(-p.z));                                           \
        aS.w += p.w / (1.f + __expf(-p.w));                                           \
        a0.x += xav.x; a0.y += xav.y; a0.z += xav.z; a0.w += xav.w;                   \
        a1.x += xcv.x; a1.y += xcv.y; a1.z += xcv.z; a1.w += xcv.w;                   \
    }

// ---- mega: fused gather (edges -> S,X0,X1 in LDS) + 2-layer MFMA FFN ----
// Block owns 8 receiver rows. Gather: 4 slots x 32 lanes; slot handles 2 rows,
// 4-deep edge unroll (12 float4 loads in flight). FFN: 16-row MFMA A-tile =
// 8 rows x 2 batches (rows 0-7 batch0 [S|X0], rows 8-15 batch1 [S|X1]);
// 2 waves split the 16 N-tiles. Grid 1536 = 6 blocks/CU x 2 waves = 12 w/CU.
__global__ __launch_bounds__(128) void mega_kernel(
        const float* __restrict__ x, const float* __restrict__ ea,
        const float* __restrict__ W1, const float* __restrict__ b1,
        const int* __restrict__ cnt, const int* __restrict__ bucket,
        const unsigned short* __restrict__ L1T, const float* __restrict__ c1,
        const unsigned short* __restrict__ L2T, const float* __restrict__ c2,
        const float* __restrict__ v, float* __restrict__ out) {
    __shared__ unsigned short Sb[8][136];
    __shared__ unsigned short X0b[8][136];
    __shared__ unsigned short X1b[8][136];
    __shared__ unsigned short T[16][264];
    int tid  = threadIdx.x;          // 0..127
    int r0   = blockIdx.x * 8;
    int slot = tid >> 5;             // 0..3
    int l32  = tid & 31;
    int q4   = l32 * 4;

    float4 w1r0 = *(const float4*)(W1 + q4);
    float4 w1r1 = *(const float4*)(W1 + 128 + q4);
    float4 w1r2 = *(const float4*)(W1 + 256 + q4);
    float4 w1r3 = *(const float4*)(W1 + 384 + q4);
    float4 bb   = *(const float4*)(b1 + q4);
    const float* xb = x + (size_t)E_ * 128;

    #pragma unroll
    for (int round = 0; round < 2; ++round) {
        int row = round * 4 + slot;          // 0..7
        int r = r0 + row;
        int cr = cnt[r];
        cr = (cr > CAP_) ? CAP_ : cr;        // impossible-overflow guard
        const int* bk = bucket + (size_t)r * CAP_;
        float4 aS = {0.f, 0.f, 0.f, 0.f};
        float4 a0 = {0.f, 0.f, 0.f, 0.f};
        float4 a1 = {0.f, 0.f, 0.f, 0.f};
        int k = 0;
        for (; k + 4 <= cr; k += 4) {
            int4 e4 = *(const int4*)(bk + k);
            float4 qv0 = *(const float4*)(ea + (size_t)e4.x * 4);
            float4 qv1 = *(const float4*)(ea + (size_t)e4.y * 4);
            float4 qv2 = *(const float4*)(ea + (size_t)e4.z * 4);
            float4 qv3 = *(const float4*)(ea + (size_t)e4.w * 4);
            float4 xa0 = *(const float4*)(x  + (size_t)e4.x * 128 + q4);
            float4 xa1 = *(const float4*)(x  + (size_t)e4.y * 128 + q4);
            float4 xa2 = *(const float4*)(x  + (size_t)e4.z * 128 + q4);
            float4 xa3 = *(const float4*)(x  + (size_t)e4.w * 128 + q4);
            float4 xc0 = *(const float4*)(xb + (size_t)e4.x * 128 + q4);
            float4 xc1 = *(const float4*)(xb + (size_t)e4.y * 128 + q4);
            float4 xc2 = *(const float4*)(xb + (size_t)e4.z * 128 + q4);
            float4 xc3 = *(const float4*)(xb + (size_t)e4.w * 128 + q4);
            EDGE_ACC(qv0, xa0, xc0);
            EDGE_ACC(qv1, xa1, xc1);
            EDGE_ACC(qv2, xa2, xc2);
            EDGE_ACC(qv3, xa3, xc3);
        }
        for (; k < cr; ++k) {
            int e0 = bk[k];
            float4 qv = *(const float4*)(ea + (size_t)e0 * 4);
            float4 xa = *(const float4*)(x  + (size_t)e0 * 128 + q4);
            float4 xc = *(const float4*)(xb + (size_t)e0 * 128 + q4);
            EDGE_ACC(qv, xa, xc);
        }
        ushort4v sS = {f2bf(aS.x), f2bf(aS.y), f2bf(aS.z), f2bf(aS.w)};
        ushort4v s0 = {f2bf(a0.x), f2bf(a0.y), f2bf(a0.z), f2bf(a0.w)};
        ushort4v s1 = {f2bf(a1.x), f2bf(a1.y), f2bf(a1.z), f2bf(a1.w)};
        *(ushort4v*)&Sb[row][q4]  = sS;
        *(ushort4v*)&X0b[row][q4] = s0;
        *(ushort4v*)&X1b[row][q4] = s1;
    }
    __syncthreads();

    // ---- FFN phase: 16 M-rows = 8 receivers x 2 batches; waves split N ----
    int wave = tid >> 6;        // nt half (0..1)
    int lane = tid & 63;
    int quad = lane >> 4;
    int l16  = lane & 15;

    float cntv[4];
    #pragma unroll
    for (int rr = 0; rr < 4; ++rr) {
        int m = quad * 4 + rr;               // M-row 0..15
        cntv[rr] = (float)cnt[r0 + (m & 7)];
    }

    short8 afrag[8];
    {
        const unsigned short* srow = &Sb[l16 & 7][0];
        const unsigned short* xrow = (l16 < 8) ? &X0b[l16 & 7][0] : &X1b[l16 & 7][0];
        #pragma unroll
        for (int ks = 0; ks < 4; ++ks) {
            afrag[ks]     = *(const short8*)(srow + quad * 8 + ks * 32);
            afrag[ks + 4] = *(const short8*)(xrow + quad * 8 + ks * 32);
        }
    }

    #pragma unroll 2
    for (int nt = wave * 8; nt < wave * 8 + 8; ++nt) {
        f32x4 acc = {0.f, 0.f, 0.f, 0.f};
        const unsigned short* bptr = L1T + (size_t)(nt * 16 + l16) * 256 + quad * 8;
        #pragma unroll
        for (int ks = 0; ks < 8; ++ks) {
            short8 bfrag = *(const short8*)(bptr + ks * 32);
            acc = __builtin_amdgcn_mfma_f32_16x16x32_bf16(afrag[ks], bfrag, acc, 0, 0, 0);
        }
        #pragma unroll
        for (int rr = 0; rr < 4; ++rr) {
            int col = nt * 16 + l16;
            float pv = acc[rr] + c1[col] + cntv[rr] * v[col];
            pv = pv / (1.f + __expf(-pv));
            T[quad * 4 + rr][col] = f2bf(pv);
        }
    }
    __syncthreads();

    short8 afrag2[8];
    #pragma unroll
    for (int ks = 0; ks < 8; ++ks)
        afrag2[ks] = *(const short8*)&T[l16][ks * 32 + quad * 8];

    #pragma unroll 2
    for (int nt = wave * 8; nt < wave * 8 + 8; ++nt) {
        f32x4 acc = {0.f, 0.f, 0.f, 0.f};
        const unsigned short* bptr = L2T + (size_t)(nt * 16 + l16) * 256 + quad * 8;
        #pragma unroll
        for (int ks = 0; ks < 8; ++ks) {
            short8 bfrag = *(const short8*)(bptr + ks * 32);
            acc = __builtin_amdgcn_mfma_f32_16x16x32_bf16(afrag2[ks], bfrag, acc, 0, 0, 0);
        }
        #pragma unroll
        for (int rr = 0; rr < 4; ++rr) {
            int m = quad * 4 + rr;           // M-row 0..15
            int b = m >> 3;
            int r = r0 + (m & 7);
            int col = nt * 16 + l16;
            out[((size_t)b * NREC_ + r) * 256 + col] = acc[rr] + c2[col];
        }
    }
}

extern "C" void kernel_launch(void* const* d_in, const int* in_sizes, int n_in,
                              void* d_out, int out_size, void* d_ws, size_t ws_size,
                              hipStream_t stream) {
    const float* x          = (const float*)d_in[0];
    const float* edge_attr  = (const float*)d_in[1];
    const int*   edge_index = (const int*)d_in[2];
    const float* W1 = (const float*)d_in[3];
    const float* b1 = (const float*)d_in[4];
    const float* W2 = (const float*)d_in[5];
    const float* b2 = (const float*)d_in[6];
    const float* L1 = (const float*)d_in[7];
    const float* c1 = (const float*)d_in[8];
    const float* L2 = (const float*)d_in[9];
    const float* c2 = (const float*)d_in[10];
    float* out = (float*)d_out;

    // workspace layout (16B aligned)
    int* cnt    = (int*)d_ws;                          // 12288 ints
    int* bucket = cnt + NREC_;                         // 12288*96 ints
    unsigned short* L1T = (unsigned short*)(bucket + (size_t)NREC_ * CAP_);  // 65536
    unsigned short* L2T = L1T + 256 * 256;             // 65536
    float* v = (float*)(L2T + 256 * 256);              // 256

    const int* recv = edge_index + E_;   // edge_index[1]

    hipMemsetAsync(cnt, 0, NREC_ * sizeof(int), stream);
    pre_fill<<<704, 256, 0, stream>>>(W2, b2, L1, L2, L1T, L2T, v, recv, cnt, bucket);
    mega_kernel<<<NREC_ / 8, 128, 0, stream>>>(x, edge_attr, W1, b1, cnt, bucket,
                                               L1T, c1, L2T, c2, v, out);
}